// Round 1
// baseline (1051.664 us; speedup 1.0000x reference)
//
#include <hip/hip_runtime.h>
#include <hip/hip_bf16.h>

#define N_ROWS 32768
#define DQ 512
#define DC 2048
#define KDIM 2048

typedef float f32x4 __attribute__((ext_vector_type(4)));
typedef short bf16x8 __attribute__((ext_vector_type(8)));

// ---------------------------------------------------------------------------
// Pack W_block [2048,2048] row-major bf16: W_blk[o][i] = sgn(ob,ib) * W_{ob^ib}[o&511][i&511]
// sign mask bit (ob*4+ib): negative. Verified vs reference Hamilton rows:
//  ob0: +r -i -j -k | ob1: +i +r +k -j | ob2: +j -k +r +i | ob3: +k +j -i +r
// ---------------------------------------------------------------------------
__global__ void pack_w_kernel(const float* __restrict__ Wr, const float* __restrict__ Wi,
                              const float* __restrict__ Wj, const float* __restrict__ Wk,
                              __hip_bfloat16* __restrict__ Wblk) {
    int idx = blockIdx.x * blockDim.x + threadIdx.x;   // 2048*2048/4 threads
    int base = idx * 4;
    int o = base >> 11;
    int i = base & 2047;
    int ob = o >> 9, ib = i >> 9;
    int oo = o & 511, ii = i & 511;
    int s = ob ^ ib;
    const float* src = (s == 0) ? Wr : (s == 1) ? Wi : (s == 2) ? Wj : Wk;
    float sgn = ((0x428E >> (ob * 4 + ib)) & 1) ? -1.0f : 1.0f;
    float4 v = *(const float4*)(src + oo * 512 + ii);
    __hip_bfloat16 outv[4];
    outv[0] = __float2bfloat16(sgn * v.x);
    outv[1] = __float2bfloat16(sgn * v.y);
    outv[2] = __float2bfloat16(sgn * v.z);
    outv[3] = __float2bfloat16(sgn * v.w);
    *(uint2*)(Wblk + base) = *(uint2*)outv;
}

__global__ void pack_bias_kernel(const float* __restrict__ b1r, const float* __restrict__ b1i,
                                 const float* __restrict__ b1j, const float* __restrict__ b1k,
                                 const float* __restrict__ b2r, const float* __restrict__ b2i,
                                 const float* __restrict__ b2j, const float* __restrict__ b2k,
                                 float* __restrict__ b1full, float* __restrict__ b2full) {
    int idx = blockIdx.x * blockDim.x + threadIdx.x;   // 2048 threads
    int c = idx >> 9, d = idx & 511;
    const float* s1 = (c == 0) ? b1r : (c == 1) ? b1i : (c == 2) ? b1j : b1k;
    const float* s2 = (c == 0) ? b2r : (c == 1) ? b2i : (c == 2) ? b2j : b2k;
    b1full[idx] = s1[d];
    b2full[idx] = s2[d];
}

// x_cat[n][c*512+d] = q_c[n][d], fp32 -> bf16. 8 elems/thread; one wave spans
// exactly one 512-col component region -> fully coalesced.
__global__ void pack_x_kernel(const float* __restrict__ qr, const float* __restrict__ qi,
                              const float* __restrict__ qj, const float* __restrict__ qk,
                              __hip_bfloat16* __restrict__ xcat) {
    int idx = blockIdx.x * blockDim.x + threadIdx.x;   // N_ROWS*DC/8 threads
    size_t base = (size_t)idx * 8;
    int col = (int)(base & 2047);
    size_t n = base >> 11;
    int c = col >> 9, d = col & 511;
    const float* src = (c == 0) ? qr : (c == 1) ? qi : (c == 2) ? qj : qk;
    const float* p = src + n * 512 + d;
    float4 v0 = *(const float4*)(p);
    float4 v1 = *(const float4*)(p + 4);
    __hip_bfloat16 o[8];
    o[0] = __float2bfloat16(v0.x); o[1] = __float2bfloat16(v0.y);
    o[2] = __float2bfloat16(v0.z); o[3] = __float2bfloat16(v0.w);
    o[4] = __float2bfloat16(v1.x); o[5] = __float2bfloat16(v1.y);
    o[6] = __float2bfloat16(v1.z); o[7] = __float2bfloat16(v1.w);
    *(uint4*)(xcat + base) = *(uint4*)o;
}

// ---------------------------------------------------------------------------
// m97-style BT GEMM: C[M,2048] = A[M,2048] @ B[2048,2048]^T (B row-major [out,in])
// 128x128 tile, BK=64, 4 waves as 2x2, each wave 4x4 of 16x16x32 bf16 MFMA.
// MODE 0: C = relu(acc+bias) -> bf16 row-major [M, 2048]
// MODE 1: C = acc+bias -> fp32 scattered into 4 blocks of [M,512] (d_out layout)
// ---------------------------------------------------------------------------
template <int MODE>
__global__ __launch_bounds__(256, 2) void qgemm_kernel(
    const __hip_bfloat16* __restrict__ A,
    const __hip_bfloat16* __restrict__ B,
    const float* __restrict__ bias,
    void* __restrict__ Cout, int M)
{
    constexpr int BM = 128, BN = 128, BK = 64;
    __shared__ short As[BM * BK];
    __shared__ short Bs[BN * BK];

    const int t = threadIdx.x;
    const int lane = t & 63;
    const int wv = t >> 6;
    const int wm = (wv >> 1) * 64;
    const int wn = (wv & 1) * 64;

    const int m0 = blockIdx.y * BM;
    const int n0 = blockIdx.x * BN;

    f32x4 acc[4][4] = {};

    // staging: thread t loads 16B at (row = i*32 + t/8, col = (t&7)*8) per issue i
    const int sr = t >> 3;
    const int sc = (t & 7) * 8;
    const short* Ag = (const short*)A + (size_t)(m0 + sr) * KDIM + sc;
    const short* Bg = (const short*)B + (size_t)(n0 + sr) * KDIM + sc;

    const int lm = lane & 15;
    const int lk = (lane >> 4) * 8;

    for (int kk = 0; kk < KDIM; kk += BK) {
#pragma unroll
        for (int i = 0; i < 4; i++) {
            __builtin_amdgcn_global_load_lds(
                (const __attribute__((address_space(1))) void*)(Ag + (size_t)i * 32 * KDIM + kk),
                (__attribute__((address_space(3))) void*)(As + i * 2048 + wv * 512),
                16, 0, 0);
            __builtin_amdgcn_global_load_lds(
                (const __attribute__((address_space(1))) void*)(Bg + (size_t)i * 32 * KDIM + kk),
                (__attribute__((address_space(3))) void*)(Bs + i * 2048 + wv * 512),
                16, 0, 0);
        }
        __syncthreads();
#pragma unroll
        for (int ks = 0; ks < 2; ks++) {
            bf16x8 af[4], bfr[4];
#pragma unroll
            for (int mi = 0; mi < 4; mi++)
                af[mi] = *(const bf16x8*)&As[(wm + mi * 16 + lm) * BK + ks * 32 + lk];
#pragma unroll
            for (int ni = 0; ni < 4; ni++)
                bfr[ni] = *(const bf16x8*)&Bs[(wn + ni * 16 + lm) * BK + ks * 32 + lk];
#pragma unroll
            for (int mi = 0; mi < 4; mi++)
#pragma unroll
                for (int ni = 0; ni < 4; ni++)
                    acc[mi][ni] = __builtin_amdgcn_mfma_f32_16x16x32_bf16(
                        af[mi], bfr[ni], acc[mi][ni], 0, 0, 0);
        }
        __syncthreads();
    }

    // epilogue: C[m][n], m = (lane>>4)*4 + r (+tile offsets), n = lane&15 (+tile offsets)
#pragma unroll
    for (int mi = 0; mi < 4; mi++) {
#pragma unroll
        for (int ni = 0; ni < 4; ni++) {
            const int n_g = n0 + wn + ni * 16 + lm;
            const float bia = bias[n_g];
#pragma unroll
            for (int r = 0; r < 4; r++) {
                const int m_g = m0 + wm + mi * 16 + (lane >> 4) * 4 + r;
                float v = acc[mi][ni][r] + bia;
                if (MODE == 0) {
                    v = fmaxf(v, 0.0f);
                    ((__hip_bfloat16*)Cout)[(size_t)m_g * DC + n_g] = __float2bfloat16(v);
                } else {
                    const int c = n_g >> 9, d = n_g & 511;
                    ((float*)Cout)[(size_t)c * ((size_t)M * DQ) + (size_t)m_g * DQ + d] = v;
                }
            }
        }
    }
}

extern "C" void kernel_launch(void* const* d_in, const int* in_sizes, int n_in,
                              void* d_out, int out_size, void* d_ws, size_t ws_size,
                              hipStream_t stream) {
    const float* qr = (const float*)d_in[0];
    const float* qi = (const float*)d_in[1];
    const float* qj = (const float*)d_in[2];
    const float* qk = (const float*)d_in[3];
    const float* W1r = (const float*)d_in[4];
    const float* W1i = (const float*)d_in[5];
    const float* W1j = (const float*)d_in[6];
    const float* W1k = (const float*)d_in[7];
    const float* W2r = (const float*)d_in[8];
    const float* W2i = (const float*)d_in[9];
    const float* W2j = (const float*)d_in[10];
    const float* W2k = (const float*)d_in[11];
    const float* b1r = (const float*)d_in[12];
    const float* b1i = (const float*)d_in[13];
    const float* b1j = (const float*)d_in[14];
    const float* b1k = (const float*)d_in[15];
    const float* b2r = (const float*)d_in[16];
    const float* b2i = (const float*)d_in[17];
    const float* b2j = (const float*)d_in[18];
    const float* b2k = (const float*)d_in[19];

    char* ws = (char*)d_ws;
    __hip_bfloat16* W1blk = (__hip_bfloat16*)ws;                       // 8 MiB
    __hip_bfloat16* W2blk = (__hip_bfloat16*)(ws + (8u << 20));        // 8 MiB
    float* b1full = (float*)(ws + (16u << 20));                        // 8 KiB
    float* b2full = b1full + 2048;                                     // 8 KiB
    __hip_bfloat16* xcat = (__hip_bfloat16*)(ws + (16u << 20) + 65536); // 128 MiB
    __hip_bfloat16* H = xcat + (size_t)N_ROWS * DC;                    // 128 MiB

    pack_w_kernel<<<(2048 * 2048 / 4) / 256, 256, 0, stream>>>(W1r, W1i, W1j, W1k, W1blk);
    pack_w_kernel<<<(2048 * 2048 / 4) / 256, 256, 0, stream>>>(W2r, W2i, W2j, W2k, W2blk);
    pack_bias_kernel<<<8, 256, 0, stream>>>(b1r, b1i, b1j, b1k, b2r, b2i, b2j, b2k, b1full, b2full);
    pack_x_kernel<<<(N_ROWS * (size_t)DC / 8) / 256, 256, 0, stream>>>(qr, qi, qj, qk, xcat);

    dim3 grid(DC / 128, N_ROWS / 128);  // x = N-tiles (16) fastest -> A-strip + full B reuse in L2
    qgemm_kernel<0><<<grid, 256, 0, stream>>>(xcat, W1blk, b1full, (void*)H, N_ROWS);
    qgemm_kernel<1><<<grid, 256, 0, stream>>>(H, W2blk, b2full, d_out, N_ROWS);
}